// Round 10
// baseline (790.794 us; speedup 1.0000x reference)
//
#include <hip/hip_runtime.h>

#define NN 50000
#define NE 800000
#define FIN 128
#define H 64
#define NG 64
#define NC 10
#define EPS 1e-5f
#define NB_SCAN 196          // ceil(NN/256)
#define GATHER_BLOCKS 12500  // NN/4 exactly
#define NGRP 8               // channel groups (8 ch each) for XCD-pinned gather
#define BNRED_BLOCKS 125     // 12500 = 125 * 100

// ---------------- degree (int) ----------------
__global__ void count_deg_kernel(const int* __restrict__ dst, int* __restrict__ deg) {
    int e = blockIdx.x * blockDim.x + threadIdx.x;
    if (e < NE) atomicAdd(&deg[dst[e]], 1);
}

// ---------------- scan stage 1 (+ dis = rsqrt(deg+1)) ----------------
__global__ void scan1_kernel(const int* __restrict__ deg, int* __restrict__ ebase,
                             int* __restrict__ bsum, float* __restrict__ dis) {
    __shared__ int s[256];
    int t = threadIdx.x;
    int i = blockIdx.x * 256 + t;
    int v = (i < NN) ? deg[i] : 0;
    if (i < NN) dis[i] = rsqrtf((float)v + 1.0f);
    s[t] = v;
    for (int off = 1; off < 256; off <<= 1) {
        __syncthreads();
        int add = (t >= off) ? s[t - off] : 0;
        __syncthreads();
        s[t] += add;
    }
    __syncthreads();
    if (i < NN) ebase[i] = s[t] - v;
    if (t == 255) bsum[blockIdx.x] = s[255];
}

// ---------------- scan stage 2 (+ graph boundaries binary search) ----------------
__global__ void scan2_kernel(int* __restrict__ bsum, const int* __restrict__ batch,
                             int* __restrict__ gstart) {
    int t = threadIdx.x;
    if (t <= NG) {  // batch is sorted
        int lo = 0, hi = NN;
        while (lo < hi) {
            int mid = (lo + hi) >> 1;
            if (batch[mid] < t) lo = mid + 1; else hi = mid;
        }
        gstart[t] = lo;
    }
    __shared__ int s[256];
    int v = (t < NB_SCAN) ? bsum[t] : 0;
    s[t] = v;
    for (int off = 1; off < 256; off <<= 1) {
        __syncthreads();
        int add = (t >= off) ? s[t - off] : 0;
        __syncthreads();
        s[t] += add;
    }
    __syncthreads();
    if (t < NB_SCAN) bsum[t] = s[t] - v;
}

__global__ void scan3_kernel(int* __restrict__ ebase, const int* __restrict__ bsum) {
    int i = blockIdx.x * blockDim.x + threadIdx.x;
    if (i < NN) ebase[i] += bsum[i >> 8];
    if (i == 0) ebase[NN] = NE;
}

// ---------------- CSR fill ----------------
__global__ void fill_kernel(const int* __restrict__ src, const int* __restrict__ dst,
                            const int* __restrict__ ebase, int* __restrict__ cursor,
                            int* __restrict__ eidx) {
    int e = blockIdx.x * blockDim.x + threadIdx.x;
    if (e < NE) {
        int d = dst[e];
        int slot = ebase[d] + atomicAdd(&cursor[d], 1);
        eidx[slot] = src[e];
    }
}

// ---------------- GEMM layer 0: hwt[g][r][c] = dis[r] * (x[r] @ W)[g*8+c] ----------------
__global__ __launch_bounds__(256, 4) void gemm_fin_kernel(const float* __restrict__ A,
                                                          const float* __restrict__ W,
                                                          const float* __restrict__ dis,
                                                          float* __restrict__ hwt) {
    __shared__ float Al[64][65];
    __shared__ float Wl[64 * H];
    const int tid = threadIdx.x;
    const int r0 = blockIdx.x * 64;
    const int row = tid >> 2;
    const int cb  = (tid & 3) << 4;
    float acc[16];
#pragma unroll
    for (int j = 0; j < 16; j++) acc[j] = 0.f;

    for (int k0 = 0; k0 < FIN; k0 += 64) {
        for (int idx = tid; idx < 64 * H; idx += 256) Wl[idx] = W[k0 * H + idx];
        for (int idx = tid; idx < 64 * 64; idx += 256) {
            int r = idx >> 6, c = idx & 63;
            int gr = r0 + r;
            Al[r][c] = (gr < NN) ? A[(long)gr * FIN + k0 + c] : 0.f;
        }
        __syncthreads();
#pragma unroll
        for (int k = 0; k < 64; k++) {
            float a = Al[row][k];
#pragma unroll
            for (int j = 0; j < 16; j++) acc[j] = fmaf(a, Wl[k * H + cb + j], acc[j]);
        }
        __syncthreads();
    }
    int gr = r0 + row;
    if (gr < NN) {
        float ds = dis[gr];
#pragma unroll
        for (int j = 0; j < 16; j++) acc[j] *= ds;
        int g0 = cb >> 3;
        float4* p0 = reinterpret_cast<float4*>(&hwt[((long)g0 * NN + gr) * 8]);
        p0[0] = make_float4(acc[0], acc[1], acc[2], acc[3]);
        p0[1] = make_float4(acc[4], acc[5], acc[6], acc[7]);
        float4* p1 = reinterpret_cast<float4*>(&hwt[((long)(g0 + 1) * NN + gr) * 8]);
        p1[0] = make_float4(acc[8], acc[9], acc[10], acc[11]);
        p1[1] = make_float4(acc[12], acc[13], acc[14], acc[15]);
    }
}

// ---------------- hidden GEMM: hwt = dis * (act(A) @ W), act from bnsc (DO_BN) ----------
template <int DO_BN>
__global__ __launch_bounds__(256, 4) void gemm_hid_kernel(const float* __restrict__ A,
                                                          const float* __restrict__ W,
                                                          const float* __restrict__ bnsc,
                                                          const float* __restrict__ dis,
                                                          float* __restrict__ hwt) {
    __shared__ float Al[64][65];
    __shared__ float Wl[64 * H];
    __shared__ float bns[128];
    const int tid = threadIdx.x;
    if (DO_BN) {
        if (tid < 128) bns[tid] = bnsc[tid];
        __syncthreads();
    }
    const int r0 = blockIdx.x * 64;
    const int row = tid >> 2;
    const int cb  = (tid & 3) << 4;
    float acc[16];
#pragma unroll
    for (int j = 0; j < 16; j++) acc[j] = 0.f;

    for (int idx = tid; idx < 64 * H; idx += 256) Wl[idx] = W[idx];
    for (int idx = tid; idx < 64 * 64; idx += 256) {
        int r = idx >> 6, c = idx & 63;
        int gr = r0 + r;
        float a = (gr < NN) ? A[(long)gr * H + c] : 0.f;
        if (DO_BN) a = fmaxf(fmaf(a, bns[c], bns[64 + c]), 0.f);
        Al[r][c] = a;
    }
    __syncthreads();
#pragma unroll
    for (int k = 0; k < 64; k++) {
        float a = Al[row][k];
#pragma unroll
        for (int j = 0; j < 16; j++) acc[j] = fmaf(a, Wl[k * H + cb + j], acc[j]);
    }
    int gr = r0 + row;
    if (gr < NN) {
        float ds = dis[gr];
#pragma unroll
        for (int j = 0; j < 16; j++) acc[j] *= ds;
        int g0 = cb >> 3;
        float4* p0 = reinterpret_cast<float4*>(&hwt[((long)g0 * NN + gr) * 8]);
        p0[0] = make_float4(acc[0], acc[1], acc[2], acc[3]);
        p0[1] = make_float4(acc[4], acc[5], acc[6], acc[7]);
        float4* p1 = reinterpret_cast<float4*>(&hwt[((long)(g0 + 1) * NN + gr) * 8]);
        p1[0] = make_float4(acc[8], acc[9], acc[10], acc[11]);
        p1[1] = make_float4(acc[12], acc[13], acc[14], acc[15]);
    }
}

// ---------------- CSR gather, channel-split + XCD-pinned --------------------------------
// grid = GATHER_BLOCKS * NGRP; grp = blockIdx & 7 (-> XCD via %8 round-robin);
// wave = 1 node: 64 lanes = 8 edges x 8 channels of sub-table hwt[grp] (1.6 MB, L2-resident)
// MODE 0: relu epilogue.  MODE 1: raw + BN partials.
template <int MODE>
__global__ __launch_bounds__(256) void gather_kernel(const float* __restrict__ hwt,
                                                     const int* __restrict__ ebase,
                                                     const int* __restrict__ eidx,
                                                     const float* __restrict__ dis,
                                                     const float* __restrict__ bias,
                                                     float* __restrict__ outp,
                                                     float* __restrict__ pbn) {
    __shared__ float ls[8], lss[8];
    const int b = blockIdx.x;
    const int grp = b & (NGRP - 1);
    const int nb  = b >> 3;                    // node block 0..12499
    const int t = threadIdx.x;
    if (MODE == 1) {
        if (t < 8) { ls[t] = 0.f; lss[t] = 0.f; }
        __syncthreads();
    }
    const int node = nb * 4 + (t >> 6);
    const int lane = t & 63;
    const int eoff = lane >> 3;                // 0..7 edge subgroup
    const int c    = lane & 7;                 // channel within group
    const float* __restrict__ tab = hwt + (long)grp * NN * 8;
    const int e0 = ebase[node], e1 = ebase[node + 1];
    float acc = 0.f;
    for (int e = e0 + eoff; e < e1; e += 8)
        acc += tab[(long)eidx[e] * 8 + c];
    acc += __shfl_xor(acc, 8, 64);
    acc += __shfl_xor(acc, 16, 64);
    acc += __shfl_xor(acc, 32, 64);
    if (eoff == 0) {
        float self = tab[(long)node * 8 + c];
        float v = fmaf(acc + self, dis[node], bias[grp * 8 + c]);
        if (MODE == 0) v = fmaxf(v, 0.f);
        outp[(long)node * H + grp * 8 + c] = v;
        if (MODE == 1) {
            atomicAdd(&ls[c], v);
            atomicAdd(&lss[c], v * v);
        }
    }
    if (MODE == 1) {
        __syncthreads();
        if (t < 8) {
            pbn[(long)nb * 128 + grp * 8 + t] = ls[t];
            pbn[(long)nb * 128 + 64 + grp * 8 + t] = lss[t];
        }
    }
}

// ---------------- BN partial reduction (coalesced): 12500x128 -> 125x128 ----------------
__global__ void bnredA_kernel(const float* __restrict__ pbn, float* __restrict__ pbn2) {
    int c = threadIdx.x & 127;
    int half = threadIdx.x >> 7;
    int r0 = blockIdx.x * 100;
    float s = 0.f;
    for (int r = r0 + half; r < r0 + 100; r += 2) s += pbn[(long)r * 128 + c];
    __shared__ float red[256];
    red[threadIdx.x] = s;
    __syncthreads();
    if (half == 0) pbn2[(long)blockIdx.x * 128 + c] = red[c] + red[128 + c];
}

// ---------------- BN finalize: 125x128 -> bnsc (scale/shift) ----------------
__global__ void bnredB_kernel(const float* __restrict__ pbn2, const float* __restrict__ gamma,
                              const float* __restrict__ beta, float* __restrict__ bnsc) {
    __shared__ float tot[128];
    int t = threadIdx.x;  // 128 threads
    float s = 0.f;
    for (int r = 0; r < BNRED_BLOCKS; ++r) s += pbn2[(long)r * 128 + t];
    tot[t] = s;
    __syncthreads();
    if (t < H) {
        float mu  = tot[t] * (1.0f / NN);
        float var = tot[H + t] * (1.0f / NN) - mu * mu;
        float sc  = rsqrtf(var + EPS) * gamma[t];
        bnsc[t]     = sc;
        bnsc[H + t] = beta[t] - mu * sc;
    }
}

// ---------------- pool stage A: 512 blocks of BN+ReLU partial sums ----------------
__global__ __launch_bounds__(256) void poolA_kernel(const float* __restrict__ conv,
                                                    const float* __restrict__ bnsc,
                                                    const int* __restrict__ gstart,
                                                    float* __restrict__ psum) {
    const int g = blockIdx.x >> 3, s = blockIdx.x & 7;
    const int n0 = gstart[g], n1 = gstart[g + 1];
    const int wave = threadIdx.x >> 6, lane = threadIdx.x & 63;
    const float sc = bnsc[lane], sh = bnsc[H + lane];
    float acc = 0.f;
    for (int n = n0 + s + 8 * wave; n < n1; n += 32)
        acc += fmaxf(fmaf(conv[(long)n * H + lane], sc, sh), 0.f);
    __shared__ float red[256];
    red[threadIdx.x] = acc;
    __syncthreads();
    if (wave == 0)
        psum[(long)blockIdx.x * H + lane] = red[lane] + red[64 + lane] + red[128 + lane] + red[192 + lane];
}

// ---------------- pool stage B + MLP readout: one wave per graph ----------------
__global__ void poolB_mlp_kernel(const float* __restrict__ psum, const int* __restrict__ gstart,
                                 const float* __restrict__ W1, const float* __restrict__ b1,
                                 const float* __restrict__ W2, const float* __restrict__ b2,
                                 const float* __restrict__ W3, const float* __restrict__ b3,
                                 float* __restrict__ out) {
    __shared__ float pl[H], y1[32], y2[16];
    const int g = blockIdx.x, t = threadIdx.x;  // 64 threads
    float s = 0.f;
#pragma unroll
    for (int k = 0; k < 8; k++) s += psum[(long)(g * 8 + k) * H + t];
    const int n0 = gstart[g], n1 = gstart[g + 1];
    pl[t] = s / fmaxf((float)(n1 - n0), 1.0f);
    __syncthreads();
    if (t < 32) {
        float v = b1[t];
        for (int k = 0; k < H; k++) v = fmaf(pl[k], W1[k * 32 + t], v);
        y1[t] = fmaxf(v, 0.f);
    }
    __syncthreads();
    if (t < 16) {
        float v = b2[t];
        for (int k = 0; k < 32; k++) v = fmaf(y1[k], W2[k * 16 + t], v);
        y2[t] = fmaxf(v, 0.f);
    }
    __syncthreads();
    if (t < NC) {
        float v = b3[t];
        for (int k = 0; k < 16; k++) v = fmaf(y2[k], W3[k * NC + t], v);
        out[(long)g * NC + t] = v;
    }
}

extern "C" void kernel_launch(void* const* d_in, const int* in_sizes, int n_in,
                              void* d_out, int out_size, void* d_ws, size_t ws_size,
                              hipStream_t stream) {
    const float* x     = (const float*)d_in[0];
    const int*   ei    = (const int*)d_in[1];
    const int*   batch = (const int*)d_in[2];
    const float* W_in  = (const float*)d_in[3];
    const float* b_in  = (const float*)d_in[4];
    const float* W_hid = (const float*)d_in[5];
    const float* b_hid = (const float*)d_in[6];
    const float* gamma = (const float*)d_in[7];
    const float* beta  = (const float*)d_in[8];
    const float* W1    = (const float*)d_in[9];
    const float* b1    = (const float*)d_in[10];
    const float* W2    = (const float*)d_in[11];
    const float* b2    = (const float*)d_in[12];
    const float* W3    = (const float*)d_in[13];
    const float* b3    = (const float*)d_in[14];
    float* out = (float*)d_out;

    const int* src = ei;
    const int* dst = ei + NE;

    // ---- workspace layout (deg|cursor adjacent -> single memset; 16B-aligned chunks) ----
    int*   deg_i  = (int*)d_ws;              // 50048
    int*   cursor = deg_i + 50048;           // 50048
    int*   ebase  = cursor + 50048;          // 50056
    int*   eidx   = ebase + 50056;           // 800000
    int*   bsum   = eidx + 800000;           // 256
    int*   gstart = bsum + 256;              // 72
    float* dis    = (float*)(gstart + 72);   // 50048
    float* hwt    = dis + 50048;             // NGRP*NN*8 = NN*64 (group-major, dis-scaled)
    float* conv   = hwt + (long)NN * H;      // NN*H
    float* h      = conv + (long)NN * H;     // NN*H
    float* pbn    = h + (long)NN * H;        // 12500*128
    float* pbn2   = pbn + (long)GATHER_BLOCKS * 128;  // 125*128
    float* bnsc   = pbn2 + BNRED_BLOCKS * 128;        // 128
    float* psum   = bnsc + 128;              // 512*64

    const int NB_GEMM = (NN + 63) / 64;        // 782
    const int NB_E    = (NE + 255) / 256;      // 3125
    const int NB_N    = (NN + 255) / 256;      // 196
    const int NB_GATH = GATHER_BLOCKS * NGRP;  // 100000

    // ---- CSR build ----
    hipMemsetAsync(deg_i, 0, 2 * 50048 * sizeof(int), stream);
    count_deg_kernel<<<NB_E, 256, 0, stream>>>(dst, deg_i);
    scan1_kernel<<<NB_SCAN, 256, 0, stream>>>(deg_i, ebase, bsum, dis);
    scan2_kernel<<<1, 256, 0, stream>>>(bsum, batch, gstart);
    scan3_kernel<<<NB_N, 256, 0, stream>>>(ebase, bsum);
    fill_kernel<<<NB_E, 256, 0, stream>>>(src, dst, ebase, cursor, eidx);

    // ---- layer 0 ----
    gemm_fin_kernel<<<NB_GEMM, 256, 0, stream>>>(x, W_in, dis, hwt);
    gather_kernel<0><<<NB_GATH, 256, 0, stream>>>(hwt, ebase, eidx, dis, b_in, h, nullptr);

    // ---- hidden layers ----
    gemm_hid_kernel<0><<<NB_GEMM, 256, 0, stream>>>(h, W_hid, nullptr, dis, hwt);
    gather_kernel<1><<<NB_GATH, 256, 0, stream>>>(hwt, ebase, eidx, dis, b_hid, conv, pbn);
    bnredA_kernel<<<BNRED_BLOCKS, 256, 0, stream>>>(pbn, pbn2);
    bnredB_kernel<<<1, 128, 0, stream>>>(pbn2, gamma, beta, bnsc);
    for (int l = 1; l < 3; l++) {
        gemm_hid_kernel<1><<<NB_GEMM, 256, 0, stream>>>(conv, W_hid + (long)l * H * H, bnsc, dis, hwt);
        gather_kernel<1><<<NB_GATH, 256, 0, stream>>>(hwt, ebase, eidx, dis,
                                                      b_hid + (long)l * H, conv, pbn);
        bnredA_kernel<<<BNRED_BLOCKS, 256, 0, stream>>>(pbn, pbn2);
        bnredB_kernel<<<1, 128, 0, stream>>>(pbn2, gamma, beta, bnsc);
    }

    // ---- pool (BN+ReLU fused) + MLP ----
    poolA_kernel<<<NG * 8, 256, 0, stream>>>(conv, bnsc, gstart, psum);
    poolB_mlp_kernel<<<NG, 64, 0, stream>>>(psum, gstart, W1, b1, W2, b2, W3, b3, out);
}

// Round 11
// 553.732 us; speedup vs baseline: 1.4281x; 1.4281x over previous
//
#include <hip/hip_runtime.h>

#define NN 50000
#define NE 800000
#define FIN 128
#define H 64
#define NG 64
#define NC 10
#define EPS 1e-5f
#define NB_SCAN 196          // ceil(NN/256)
#define GATHER_BLOCKS 12500  // NN/4 exactly
#define BNRED_BLOCKS 125     // 12500 = 125 * 100

// ---------------- degree (int) ----------------
__global__ void count_deg_kernel(const int* __restrict__ dst, int* __restrict__ deg) {
    int e = blockIdx.x * blockDim.x + threadIdx.x;
    if (e < NE) atomicAdd(&deg[dst[e]], 1);
}

// ---------------- scan stage 1 (+ dis = rsqrt(deg+1)) ----------------
__global__ void scan1_kernel(const int* __restrict__ deg, int* __restrict__ ebase,
                             int* __restrict__ bsum, float* __restrict__ dis) {
    __shared__ int s[256];
    int t = threadIdx.x;
    int i = blockIdx.x * 256 + t;
    int v = (i < NN) ? deg[i] : 0;
    if (i < NN) dis[i] = rsqrtf((float)v + 1.0f);
    s[t] = v;
    for (int off = 1; off < 256; off <<= 1) {
        __syncthreads();
        int add = (t >= off) ? s[t - off] : 0;
        __syncthreads();
        s[t] += add;
    }
    __syncthreads();
    if (i < NN) ebase[i] = s[t] - v;
    if (t == 255) bsum[blockIdx.x] = s[255];
}

// ---------------- scan stage 2 (+ graph boundaries binary search) ----------------
__global__ void scan2_kernel(int* __restrict__ bsum, const int* __restrict__ batch,
                             int* __restrict__ gstart) {
    int t = threadIdx.x;
    if (t <= NG) {  // batch is sorted
        int lo = 0, hi = NN;
        while (lo < hi) {
            int mid = (lo + hi) >> 1;
            if (batch[mid] < t) lo = mid + 1; else hi = mid;
        }
        gstart[t] = lo;
    }
    __shared__ int s[256];
    int v = (t < NB_SCAN) ? bsum[t] : 0;
    s[t] = v;
    for (int off = 1; off < 256; off <<= 1) {
        __syncthreads();
        int add = (t >= off) ? s[t - off] : 0;
        __syncthreads();
        s[t] += add;
    }
    __syncthreads();
    if (t < NB_SCAN) bsum[t] = s[t] - v;
}

__global__ void scan3_kernel(int* __restrict__ ebase, const int* __restrict__ bsum) {
    int i = blockIdx.x * blockDim.x + threadIdx.x;
    if (i < NN) ebase[i] += bsum[i >> 8];
    if (i == 0) ebase[NN] = NE;
}

// ---------------- CSR fill ----------------
__global__ void fill_kernel(const int* __restrict__ src, const int* __restrict__ dst,
                            const int* __restrict__ ebase, int* __restrict__ cursor,
                            int* __restrict__ eidx) {
    int e = blockIdx.x * blockDim.x + threadIdx.x;
    if (e < NE) {
        int d = dst[e];
        int slot = ebase[d] + atomicAdd(&cursor[d], 1);
        eidx[slot] = src[e];
    }
}

// ---------------- GEMM layer 0: hw[r] = dis[r] * (x[r] @ W) ----------------
__global__ __launch_bounds__(256, 4) void gemm_fin_kernel(const float* __restrict__ A,
                                                          const float* __restrict__ W,
                                                          const float* __restrict__ dis,
                                                          float* __restrict__ outp) {
    __shared__ float Al[64][65];
    __shared__ float Wl[64 * H];
    const int tid = threadIdx.x;
    const int r0 = blockIdx.x * 64;
    const int row = tid >> 2;
    const int cb  = (tid & 3) << 4;
    float acc[16];
#pragma unroll
    for (int j = 0; j < 16; j++) acc[j] = 0.f;

    for (int k0 = 0; k0 < FIN; k0 += 64) {
        // W tile: 64x64 floats = 1024 float4s
        for (int idx = tid; idx < 64 * 16; idx += 256) {
            float4 w = *reinterpret_cast<const float4*>(&W[k0 * H + idx * 4]);
            *reinterpret_cast<float4*>(&Wl[idx * 4]) = w;
        }
        // A tile: 64 rows x 16 float4s
        for (int idx = tid; idx < 64 * 16; idx += 256) {
            int r = idx >> 4, c4 = (idx & 15) << 2;
            int gr = r0 + r;
            float4 a = make_float4(0.f, 0.f, 0.f, 0.f);
            if (gr < NN) a = *reinterpret_cast<const float4*>(&A[(long)gr * FIN + k0 + c4]);
            Al[r][c4 + 0] = a.x; Al[r][c4 + 1] = a.y;
            Al[r][c4 + 2] = a.z; Al[r][c4 + 3] = a.w;
        }
        __syncthreads();
#pragma unroll
        for (int k = 0; k < 64; k++) {
            float a = Al[row][k];
#pragma unroll
            for (int j = 0; j < 16; j++) acc[j] = fmaf(a, Wl[k * H + cb + j], acc[j]);
        }
        __syncthreads();
    }
    int gr = r0 + row;
    if (gr < NN) {
        float ds = dis[gr];
#pragma unroll
        for (int j = 0; j < 16; j++) acc[j] *= ds;
        float4* o = reinterpret_cast<float4*>(&outp[(long)gr * H + cb]);
        o[0] = make_float4(acc[0], acc[1], acc[2], acc[3]);
        o[1] = make_float4(acc[4], acc[5], acc[6], acc[7]);
        o[2] = make_float4(acc[8], acc[9], acc[10], acc[11]);
        o[3] = make_float4(acc[12], acc[13], acc[14], acc[15]);
    }
}

// ---------------- hidden GEMM: hw[r] = dis[r] * (act(A[r]) @ W) ----------------
// DO_BN=1: act(a) = relu(a*bnsc[c] + bnsc[64+c]) applied during A staging
template <int DO_BN>
__global__ __launch_bounds__(256, 4) void gemm_hid_kernel(const float* __restrict__ A,
                                                          const float* __restrict__ W,
                                                          const float* __restrict__ bnsc,
                                                          const float* __restrict__ dis,
                                                          float* __restrict__ outp) {
    __shared__ float Al[64][65];
    __shared__ float Wl[64 * H];
    __shared__ float bns[128];
    const int tid = threadIdx.x;
    if (DO_BN) {
        if (tid < 128) bns[tid] = bnsc[tid];
        __syncthreads();
    }
    const int r0 = blockIdx.x * 64;
    const int row = tid >> 2;
    const int cb  = (tid & 3) << 4;
    float acc[16];
#pragma unroll
    for (int j = 0; j < 16; j++) acc[j] = 0.f;

    for (int idx = tid; idx < 64 * 16; idx += 256) {
        float4 w = *reinterpret_cast<const float4*>(&W[idx * 4]);
        *reinterpret_cast<float4*>(&Wl[idx * 4]) = w;
    }
    for (int idx = tid; idx < 64 * 16; idx += 256) {
        int r = idx >> 4, c4 = (idx & 15) << 2;
        int gr = r0 + r;
        float4 a = make_float4(0.f, 0.f, 0.f, 0.f);
        if (gr < NN) a = *reinterpret_cast<const float4*>(&A[(long)gr * H + c4]);
        if (DO_BN) {
            a.x = fmaxf(fmaf(a.x, bns[c4 + 0], bns[64 + c4 + 0]), 0.f);
            a.y = fmaxf(fmaf(a.y, bns[c4 + 1], bns[64 + c4 + 1]), 0.f);
            a.z = fmaxf(fmaf(a.z, bns[c4 + 2], bns[64 + c4 + 2]), 0.f);
            a.w = fmaxf(fmaf(a.w, bns[c4 + 3], bns[64 + c4 + 3]), 0.f);
        }
        Al[r][c4 + 0] = a.x; Al[r][c4 + 1] = a.y;
        Al[r][c4 + 2] = a.z; Al[r][c4 + 3] = a.w;
    }
    __syncthreads();
#pragma unroll
    for (int k = 0; k < 64; k++) {
        float a = Al[row][k];
#pragma unroll
        for (int j = 0; j < 16; j++) acc[j] = fmaf(a, Wl[k * H + cb + j], acc[j]);
    }
    int gr = r0 + row;
    if (gr < NN) {
        float ds = dis[gr];
#pragma unroll
        for (int j = 0; j < 16; j++) acc[j] *= ds;
        float4* o = reinterpret_cast<float4*>(&outp[(long)gr * H + cb]);
        o[0] = make_float4(acc[0], acc[1], acc[2], acc[3]);
        o[1] = make_float4(acc[4], acc[5], acc[6], acc[7]);
        o[2] = make_float4(acc[8], acc[9], acc[10], acc[11]);
        o[3] = make_float4(acc[12], acc[13], acc[14], acc[15]);
    }
}

// ---------------- CSR gather: wave/node, 16 lanes x float4, 4 edge groups, x4 unroll --
// out_i = dis_i * (sum_{j in N(i)} hw'_j + hw'_i) + b   where hw' rows carry dis_j
// MODE 0: relu epilogue (layer 0).  MODE 1: raw + BN partials (hidden).
template <int MODE>
__global__ __launch_bounds__(256) void gather_kernel(const float* __restrict__ hw,
                                                     const int* __restrict__ ebase,
                                                     const int* __restrict__ eidx,
                                                     const float* __restrict__ dis,
                                                     const float* __restrict__ bias,
                                                     float* __restrict__ outp,
                                                     float* __restrict__ pbn) {
    __shared__ float ls[H], lss[H];
    if (MODE == 1) {
        if (threadIdx.x < H) { ls[threadIdx.x] = 0.f; lss[threadIdx.x] = 0.f; }
        __syncthreads();
    }
    const int node = blockIdx.x * 4 + (threadIdx.x >> 6);  // grid exact: node < NN
    const int lane = threadIdx.x & 63;
    const int grp  = lane >> 4;          // edge sub-group 0..3
    const int c4   = (lane & 15) << 2;   // channel base
    const int e0 = ebase[node], e1 = ebase[node + 1];
    float4 acc = make_float4(0.f, 0.f, 0.f, 0.f);
    int e = e0 + grp;
    // 4 independent row loads in flight per lane
    for (; e + 12 < e1; e += 16) {
        int s0 = eidx[e], s1 = eidx[e + 4], s2 = eidx[e + 8], s3 = eidx[e + 12];
        const float4 v0 = *reinterpret_cast<const float4*>(&hw[(long)s0 * H + c4]);
        const float4 v1 = *reinterpret_cast<const float4*>(&hw[(long)s1 * H + c4]);
        const float4 v2 = *reinterpret_cast<const float4*>(&hw[(long)s2 * H + c4]);
        const float4 v3 = *reinterpret_cast<const float4*>(&hw[(long)s3 * H + c4]);
        acc.x += (v0.x + v1.x) + (v2.x + v3.x);
        acc.y += (v0.y + v1.y) + (v2.y + v3.y);
        acc.z += (v0.z + v1.z) + (v2.z + v3.z);
        acc.w += (v0.w + v1.w) + (v2.w + v3.w);
    }
    for (; e < e1; e += 4) {
        const float4 v0 = *reinterpret_cast<const float4*>(&hw[(long)eidx[e] * H + c4]);
        acc.x += v0.x; acc.y += v0.y; acc.z += v0.z; acc.w += v0.w;
    }
#pragma unroll
    for (int m = 16; m <= 32; m <<= 1) {
        acc.x += __shfl_xor(acc.x, m, 64);
        acc.y += __shfl_xor(acc.y, m, 64);
        acc.z += __shfl_xor(acc.z, m, 64);
        acc.w += __shfl_xor(acc.w, m, 64);
    }
    const float4 self = *reinterpret_cast<const float4*>(&hw[(long)node * H + c4]);
    float ds = dis[node];
    float4 v;
    v.x = fmaf(acc.x + self.x, ds, bias[c4 + 0]);
    v.y = fmaf(acc.y + self.y, ds, bias[c4 + 1]);
    v.z = fmaf(acc.z + self.z, ds, bias[c4 + 2]);
    v.w = fmaf(acc.w + self.w, ds, bias[c4 + 3]);
    if (MODE == 0) {
        v.x = fmaxf(v.x, 0.f); v.y = fmaxf(v.y, 0.f);
        v.z = fmaxf(v.z, 0.f); v.w = fmaxf(v.w, 0.f);
    }
    if (grp == 0) {
        *reinterpret_cast<float4*>(&outp[(long)node * H + c4]) = v;
        if (MODE == 1) {
            atomicAdd(&ls[c4 + 0], v.x); atomicAdd(&lss[c4 + 0], v.x * v.x);
            atomicAdd(&ls[c4 + 1], v.y); atomicAdd(&lss[c4 + 1], v.y * v.y);
            atomicAdd(&ls[c4 + 2], v.z); atomicAdd(&lss[c4 + 2], v.z * v.z);
            atomicAdd(&ls[c4 + 3], v.w); atomicAdd(&lss[c4 + 3], v.w * v.w);
        }
    }
    if (MODE == 1) {
        __syncthreads();
        if (threadIdx.x < H) {
            pbn[(long)blockIdx.x * 128 + threadIdx.x] = ls[threadIdx.x];
            pbn[(long)blockIdx.x * 128 + H + threadIdx.x] = lss[threadIdx.x];
        }
    }
}

// ---------------- BN partial reduction (coalesced): 12500x128 -> 125x128 ----------------
__global__ void bnredA_kernel(const float* __restrict__ pbn, float* __restrict__ pbn2) {
    int c = threadIdx.x & 127;
    int half = threadIdx.x >> 7;
    int r0 = blockIdx.x * 100;
    float s = 0.f;
    for (int r = r0 + half; r < r0 + 100; r += 2) s += pbn[(long)r * 128 + c];
    __shared__ float red[256];
    red[threadIdx.x] = s;
    __syncthreads();
    if (half == 0) pbn2[(long)blockIdx.x * 128 + c] = red[c] + red[128 + c];
}

// ---------------- BN finalize: 125x128 -> bnsc (scale/shift) ----------------
__global__ void bnredB_kernel(const float* __restrict__ pbn2, const float* __restrict__ gamma,
                              const float* __restrict__ beta, float* __restrict__ bnsc) {
    __shared__ float tot[128];
    int t = threadIdx.x;  // 128 threads
    float s = 0.f;
    for (int r = 0; r < BNRED_BLOCKS; ++r) s += pbn2[(long)r * 128 + t];
    tot[t] = s;
    __syncthreads();
    if (t < H) {
        float mu  = tot[t] * (1.0f / NN);
        float var = tot[H + t] * (1.0f / NN) - mu * mu;
        float sc  = rsqrtf(var + EPS) * gamma[t];
        bnsc[t]     = sc;
        bnsc[H + t] = beta[t] - mu * sc;
    }
}

// ---------------- pool stage A: 512 blocks of BN+ReLU partial sums ----------------
__global__ __launch_bounds__(256) void poolA_kernel(const float* __restrict__ conv,
                                                    const float* __restrict__ bnsc,
                                                    const int* __restrict__ gstart,
                                                    float* __restrict__ psum) {
    const int g = blockIdx.x >> 3, s = blockIdx.x & 7;
    const int n0 = gstart[g], n1 = gstart[g + 1];
    const int wave = threadIdx.x >> 6, lane = threadIdx.x & 63;
    const float sc = bnsc[lane], sh = bnsc[H + lane];
    float acc = 0.f;
    for (int n = n0 + s + 8 * wave; n < n1; n += 32)
        acc += fmaxf(fmaf(conv[(long)n * H + lane], sc, sh), 0.f);
    __shared__ float red[256];
    red[threadIdx.x] = acc;
    __syncthreads();
    if (wave == 0)
        psum[(long)blockIdx.x * H + lane] = red[lane] + red[64 + lane] + red[128 + lane] + red[192 + lane];
}

// ---------------- pool stage B + MLP readout: one wave per graph ----------------
__global__ void poolB_mlp_kernel(const float* __restrict__ psum, const int* __restrict__ gstart,
                                 const float* __restrict__ W1, const float* __restrict__ b1,
                                 const float* __restrict__ W2, const float* __restrict__ b2,
                                 const float* __restrict__ W3, const float* __restrict__ b3,
                                 float* __restrict__ out) {
    __shared__ float pl[H], y1[32], y2[16];
    const int g = blockIdx.x, t = threadIdx.x;  // 64 threads
    float s = 0.f;
#pragma unroll
    for (int k = 0; k < 8; k++) s += psum[(long)(g * 8 + k) * H + t];
    const int n0 = gstart[g], n1 = gstart[g + 1];
    pl[t] = s / fmaxf((float)(n1 - n0), 1.0f);
    __syncthreads();
    if (t < 32) {
        float v = b1[t];
        for (int k = 0; k < H; k++) v = fmaf(pl[k], W1[k * 32 + t], v);
        y1[t] = fmaxf(v, 0.f);
    }
    __syncthreads();
    if (t < 16) {
        float v = b2[t];
        for (int k = 0; k < 32; k++) v = fmaf(y1[k], W2[k * 16 + t], v);
        y2[t] = fmaxf(v, 0.f);
    }
    __syncthreads();
    if (t < NC) {
        float v = b3[t];
        for (int k = 0; k < 16; k++) v = fmaf(y2[k], W3[k * NC + t], v);
        out[(long)g * NC + t] = v;
    }
}

extern "C" void kernel_launch(void* const* d_in, const int* in_sizes, int n_in,
                              void* d_out, int out_size, void* d_ws, size_t ws_size,
                              hipStream_t stream) {
    const float* x     = (const float*)d_in[0];
    const int*   ei    = (const int*)d_in[1];
    const int*   batch = (const int*)d_in[2];
    const float* W_in  = (const float*)d_in[3];
    const float* b_in  = (const float*)d_in[4];
    const float* W_hid = (const float*)d_in[5];
    const float* b_hid = (const float*)d_in[6];
    const float* gamma = (const float*)d_in[7];
    const float* beta  = (const float*)d_in[8];
    const float* W1    = (const float*)d_in[9];
    const float* b1    = (const float*)d_in[10];
    const float* W2    = (const float*)d_in[11];
    const float* b2    = (const float*)d_in[12];
    const float* W3    = (const float*)d_in[13];
    const float* b3    = (const float*)d_in[14];
    float* out = (float*)d_out;

    const int* src = ei;
    const int* dst = ei + NE;

    // ---- workspace layout (deg|cursor adjacent -> single memset; 16B-aligned chunks) ----
    int*   deg_i  = (int*)d_ws;              // 50048
    int*   cursor = deg_i + 50048;           // 50048
    int*   ebase  = cursor + 50048;          // 50056
    int*   eidx   = ebase + 50056;           // 800000
    int*   bsum   = eidx + 800000;           // 256
    int*   gstart = bsum + 256;              // 72
    float* dis    = (float*)(gstart + 72);   // 50048
    float* hw     = dis + 50048;             // NN*H (dis-scaled rows)
    float* conv   = hw + (long)NN * H;       // NN*H
    float* h      = conv + (long)NN * H;     // NN*H
    float* pbn    = h + (long)NN * H;        // 12500*128
    float* pbn2   = pbn + (long)GATHER_BLOCKS * 128;  // 125*128
    float* bnsc   = pbn2 + BNRED_BLOCKS * 128;        // 128
    float* psum   = bnsc + 128;              // 512*64

    const int NB_GEMM = (NN + 63) / 64;        // 782
    const int NB_E    = (NE + 255) / 256;      // 3125
    const int NB_N    = (NN + 255) / 256;      // 196

    // ---- CSR build ----
    hipMemsetAsync(deg_i, 0, 2 * 50048 * sizeof(int), stream);
    count_deg_kernel<<<NB_E, 256, 0, stream>>>(dst, deg_i);
    scan1_kernel<<<NB_SCAN, 256, 0, stream>>>(deg_i, ebase, bsum, dis);
    scan2_kernel<<<1, 256, 0, stream>>>(bsum, batch, gstart);
    scan3_kernel<<<NB_N, 256, 0, stream>>>(ebase, bsum);
    fill_kernel<<<NB_E, 256, 0, stream>>>(src, dst, ebase, cursor, eidx);

    // ---- layer 0 ----
    gemm_fin_kernel<<<NB_GEMM, 256, 0, stream>>>(x, W_in, dis, hw);
    gather_kernel<0><<<GATHER_BLOCKS, 256, 0, stream>>>(hw, ebase, eidx, dis, b_in, h, nullptr);

    // ---- hidden layers ----
    gemm_hid_kernel<0><<<NB_GEMM, 256, 0, stream>>>(h, W_hid, nullptr, dis, hw);
    gather_kernel<1><<<GATHER_BLOCKS, 256, 0, stream>>>(hw, ebase, eidx, dis, b_hid, conv, pbn);
    bnredA_kernel<<<BNRED_BLOCKS, 256, 0, stream>>>(pbn, pbn2);
    bnredB_kernel<<<1, 128, 0, stream>>>(pbn2, gamma, beta, bnsc);
    for (int l = 1; l < 3; l++) {
        gemm_hid_kernel<1><<<NB_GEMM, 256, 0, stream>>>(conv, W_hid + (long)l * H * H, bnsc, dis, hw);
        gather_kernel<1><<<GATHER_BLOCKS, 256, 0, stream>>>(hw, ebase, eidx, dis,
                                                            b_hid + (long)l * H, conv, pbn);
        bnredA_kernel<<<BNRED_BLOCKS, 256, 0, stream>>>(pbn, pbn2);
        bnredB_kernel<<<1, 128, 0, stream>>>(pbn2, gamma, beta, bnsc);
    }

    // ---- pool (BN+ReLU fused) + MLP ----
    poolA_kernel<<<NG * 8, 256, 0, stream>>>(conv, bnsc, gstart, psum);
    poolB_mlp_kernel<<<NG, 64, 0, stream>>>(psum, gstart, W1, b1, W2, b2, W3, b3, out);
}

// Round 13
// 540.620 us; speedup vs baseline: 1.4628x; 1.0243x over previous
//
#include <hip/hip_runtime.h>
#include <hip/hip_fp16.h>

#define NN 50000
#define NE 800000
#define FIN 128
#define H 64
#define NG 64
#define NC 10
#define EPS 1e-5f
#define NB_SCAN 196          // ceil(NN/256)
#define GATHER_BLOCKS 12500  // NN/4 exactly
#define BNRED_BLOCKS 125     // 12500 = 125 * 100

// ---------------- degree (int) ----------------
__global__ void count_deg_kernel(const int* __restrict__ dst, int* __restrict__ deg) {
    int e = blockIdx.x * blockDim.x + threadIdx.x;
    if (e < NE) atomicAdd(&deg[dst[e]], 1);
}

// ---------------- scan stage 1 (+ dis = rsqrt(deg+1)) ----------------
__global__ void scan1_kernel(const int* __restrict__ deg, int* __restrict__ ebase,
                             int* __restrict__ bsum, float* __restrict__ dis) {
    __shared__ int s[256];
    int t = threadIdx.x;
    int i = blockIdx.x * 256 + t;
    int v = (i < NN) ? deg[i] : 0;
    if (i < NN) dis[i] = rsqrtf((float)v + 1.0f);
    s[t] = v;
    for (int off = 1; off < 256; off <<= 1) {
        __syncthreads();
        int add = (t >= off) ? s[t - off] : 0;
        __syncthreads();
        s[t] += add;
    }
    __syncthreads();
    if (i < NN) ebase[i] = s[t] - v;
    if (t == 255) bsum[blockIdx.x] = s[255];
}

// ---------------- scan stage 2 (+ graph boundaries binary search) ----------------
__global__ void scan2_kernel(int* __restrict__ bsum, const int* __restrict__ batch,
                             int* __restrict__ gstart) {
    int t = threadIdx.x;
    if (t <= NG) {  // batch is sorted
        int lo = 0, hi = NN;
        while (lo < hi) {
            int mid = (lo + hi) >> 1;
            if (batch[mid] < t) lo = mid + 1; else hi = mid;
        }
        gstart[t] = lo;
    }
    __shared__ int s[256];
    int v = (t < NB_SCAN) ? bsum[t] : 0;
    s[t] = v;
    for (int off = 1; off < 256; off <<= 1) {
        __syncthreads();
        int add = (t >= off) ? s[t - off] : 0;
        __syncthreads();
        s[t] += add;
    }
    __syncthreads();
    if (t < NB_SCAN) bsum[t] = s[t] - v;
}

__global__ void scan3_kernel(int* __restrict__ ebase, const int* __restrict__ bsum) {
    int i = blockIdx.x * blockDim.x + threadIdx.x;
    if (i < NN) ebase[i] += bsum[i >> 8];
    if (i == 0) ebase[NN] = NE;
}

// ---------------- CSR fill ----------------
__global__ void fill_kernel(const int* __restrict__ src, const int* __restrict__ dst,
                            const int* __restrict__ ebase, int* __restrict__ cursor,
                            int* __restrict__ eidx) {
    int e = blockIdx.x * blockDim.x + threadIdx.x;
    if (e < NE) {
        int d = dst[e];
        int slot = ebase[d] + atomicAdd(&cursor[d], 1);
        eidx[slot] = src[e];
    }
}

// ---------------- GEMM layer 0: hw16[r] = fp16(dis[r] * (x[r] @ W)) ----------------
__global__ __launch_bounds__(256, 4) void gemm_fin_kernel(const float* __restrict__ A,
                                                          const float* __restrict__ W,
                                                          const float* __restrict__ dis,
                                                          __half* __restrict__ outp) {
    __shared__ float Al[64][65];
    __shared__ float Wl[64 * H];
    const int tid = threadIdx.x;
    const int r0 = blockIdx.x * 64;
    const int row = tid >> 2;
    const int cb  = (tid & 3) << 4;
    float acc[16];
#pragma unroll
    for (int j = 0; j < 16; j++) acc[j] = 0.f;

    for (int k0 = 0; k0 < FIN; k0 += 64) {
        for (int idx = tid; idx < 64 * 16; idx += 256) {
            float4 w = *reinterpret_cast<const float4*>(&W[k0 * H + idx * 4]);
            *reinterpret_cast<float4*>(&Wl[idx * 4]) = w;
        }
        for (int idx = tid; idx < 64 * 16; idx += 256) {
            int r = idx >> 4, c4 = (idx & 15) << 2;
            int gr = r0 + r;
            float4 a = make_float4(0.f, 0.f, 0.f, 0.f);
            if (gr < NN) a = *reinterpret_cast<const float4*>(&A[(long)gr * FIN + k0 + c4]);
            Al[r][c4 + 0] = a.x; Al[r][c4 + 1] = a.y;
            Al[r][c4 + 2] = a.z; Al[r][c4 + 3] = a.w;
        }
        __syncthreads();
#pragma unroll
        for (int k = 0; k < 64; k++) {
            float a = Al[row][k];
#pragma unroll
            for (int j = 0; j < 16; j++) acc[j] = fmaf(a, Wl[k * H + cb + j], acc[j]);
        }
        __syncthreads();
    }
    int gr = r0 + row;
    if (gr < NN) {
        float ds = dis[gr];
        __half hb[16];
#pragma unroll
        for (int j = 0; j < 16; j++) hb[j] = __float2half(acc[j] * ds);
        int4* o = reinterpret_cast<int4*>(&outp[(long)gr * H + cb]);
        o[0] = *reinterpret_cast<int4*>(&hb[0]);
        o[1] = *reinterpret_cast<int4*>(&hb[8]);
    }
}

// ---------------- hidden GEMM: hw16[r] = fp16(dis[r] * (act(A[r]) @ W)) ----------------
// DO_BN=1: act(a) = relu(a*bnsc[c] + bnsc[64+c]) applied during A staging
template <int DO_BN>
__global__ __launch_bounds__(256, 4) void gemm_hid_kernel(const float* __restrict__ A,
                                                          const float* __restrict__ W,
                                                          const float* __restrict__ bnsc,
                                                          const float* __restrict__ dis,
                                                          __half* __restrict__ outp) {
    __shared__ float Al[64][65];
    __shared__ float Wl[64 * H];
    __shared__ float bns[128];
    const int tid = threadIdx.x;
    if (DO_BN) {
        if (tid < 128) bns[tid] = bnsc[tid];
        __syncthreads();
    }
    const int r0 = blockIdx.x * 64;
    const int row = tid >> 2;
    const int cb  = (tid & 3) << 4;
    float acc[16];
#pragma unroll
    for (int j = 0; j < 16; j++) acc[j] = 0.f;

    for (int idx = tid; idx < 64 * 16; idx += 256) {
        float4 w = *reinterpret_cast<const float4*>(&W[idx * 4]);
        *reinterpret_cast<float4*>(&Wl[idx * 4]) = w;
    }
    for (int idx = tid; idx < 64 * 16; idx += 256) {
        int r = idx >> 4, c4 = (idx & 15) << 2;
        int gr = r0 + r;
        float4 a = make_float4(0.f, 0.f, 0.f, 0.f);
        if (gr < NN) a = *reinterpret_cast<const float4*>(&A[(long)gr * H + c4]);
        if (DO_BN) {
            a.x = fmaxf(fmaf(a.x, bns[c4 + 0], bns[64 + c4 + 0]), 0.f);
            a.y = fmaxf(fmaf(a.y, bns[c4 + 1], bns[64 + c4 + 1]), 0.f);
            a.z = fmaxf(fmaf(a.z, bns[c4 + 2], bns[64 + c4 + 2]), 0.f);
            a.w = fmaxf(fmaf(a.w, bns[c4 + 3], bns[64 + c4 + 3]), 0.f);
        }
        Al[r][c4 + 0] = a.x; Al[r][c4 + 1] = a.y;
        Al[r][c4 + 2] = a.z; Al[r][c4 + 3] = a.w;
    }
    __syncthreads();
#pragma unroll
    for (int k = 0; k < 64; k++) {
        float a = Al[row][k];
#pragma unroll
        for (int j = 0; j < 16; j++) acc[j] = fmaf(a, Wl[k * H + cb + j], acc[j]);
    }
    int gr = r0 + row;
    if (gr < NN) {
        float ds = dis[gr];
        __half hb[16];
#pragma unroll
        for (int j = 0; j < 16; j++) hb[j] = __float2half(acc[j] * ds);
        int4* o = reinterpret_cast<int4*>(&outp[(long)gr * H + cb]);
        o[0] = *reinterpret_cast<int4*>(&hb[0]);
        o[1] = *reinterpret_cast<int4*>(&hb[8]);
    }
}

// ---------------- CSR gather (fp16 table): wave/node, 8 edge-grps x 8 lanes x 8 ch ------
// out_i = dis_i * (sum_j hw16_j + hw16_i) + b ; f32 accumulate.
// MODE 0: relu epilogue (layer 0).  MODE 1: raw + BN partials (hidden).
template <int MODE>
__global__ __launch_bounds__(256) void gather_kernel(const __half* __restrict__ hw,
                                                     const int* __restrict__ ebase,
                                                     const int* __restrict__ eidx,
                                                     const float* __restrict__ dis,
                                                     const float* __restrict__ bias,
                                                     float* __restrict__ outp,
                                                     float* __restrict__ pbn) {
    __shared__ float ls[H], lss[H];
    if (MODE == 1) {
        if (threadIdx.x < H) { ls[threadIdx.x] = 0.f; lss[threadIdx.x] = 0.f; }
        __syncthreads();
    }
    const int node = blockIdx.x * 4 + (threadIdx.x >> 6);  // grid exact: node < NN
    const int lane = threadIdx.x & 63;
    const int eg   = lane >> 3;          // edge sub-group 0..7
    const int c8   = (lane & 7) << 3;    // channel base (8 ch/lane)
    const int e0 = ebase[node], e1 = ebase[node + 1];
    float a[8];
#pragma unroll
    for (int j = 0; j < 8; j++) a[j] = 0.f;

    int e = e0 + eg;
    for (; e + 8 < e1; e += 16) {   // 2 rows in flight
        int s0 = eidx[e], s1 = eidx[e + 8];
        int4 r0 = *reinterpret_cast<const int4*>(&hw[(long)s0 * H + c8]);
        int4 r1 = *reinterpret_cast<const int4*>(&hw[(long)s1 * H + c8]);
#pragma unroll
        for (int q = 0; q < 4; q++) {
            float2 f0 = __half22float2(reinterpret_cast<const __half2*>(&r0)[q]);
            float2 f1 = __half22float2(reinterpret_cast<const __half2*>(&r1)[q]);
            a[2 * q + 0] += f0.x + f1.x;
            a[2 * q + 1] += f0.y + f1.y;
        }
    }
    for (; e < e1; e += 8) {
        int4 r0 = *reinterpret_cast<const int4*>(&hw[(long)eidx[e] * H + c8]);
#pragma unroll
        for (int q = 0; q < 4; q++) {
            float2 f0 = __half22float2(reinterpret_cast<const __half2*>(&r0)[q]);
            a[2 * q + 0] += f0.x;
            a[2 * q + 1] += f0.y;
        }
    }
#pragma unroll
    for (int m = 8; m <= 32; m <<= 1) {
#pragma unroll
        for (int j = 0; j < 8; j++) a[j] += __shfl_xor(a[j], m, 64);
    }
    if (eg == 0) {                      // lanes 0..7 hold full sums for their 8 channels
        int4 sr = *reinterpret_cast<const int4*>(&hw[(long)node * H + c8]);
        float ds = dis[node];
        float v[8];
#pragma unroll
        for (int q = 0; q < 4; q++) {
            float2 fs = __half22float2(reinterpret_cast<const __half2*>(&sr)[q]);
            v[2 * q + 0] = fmaf(a[2 * q + 0] + fs.x, ds, bias[c8 + 2 * q + 0]);
            v[2 * q + 1] = fmaf(a[2 * q + 1] + fs.y, ds, bias[c8 + 2 * q + 1]);
        }
        if (MODE == 0) {
#pragma unroll
            for (int j = 0; j < 8; j++) v[j] = fmaxf(v[j], 0.f);
        }
        float4* o = reinterpret_cast<float4*>(&outp[(long)node * H + c8]);
        o[0] = make_float4(v[0], v[1], v[2], v[3]);
        o[1] = make_float4(v[4], v[5], v[6], v[7]);
        if (MODE == 1) {
#pragma unroll
            for (int j = 0; j < 8; j++) {
                atomicAdd(&ls[c8 + j], v[j]);
                atomicAdd(&lss[c8 + j], v[j] * v[j]);
            }
        }
    }
    if (MODE == 1) {
        __syncthreads();
        if (threadIdx.x < H) {
            pbn[(long)blockIdx.x * 128 + threadIdx.x] = ls[threadIdx.x];
            pbn[(long)blockIdx.x * 128 + H + threadIdx.x] = lss[threadIdx.x];
        }
    }
}

// ---------------- BN partial reduction (coalesced): 12500x128 -> 125x128 ----------------
__global__ void bnredA_kernel(const float* __restrict__ pbn, float* __restrict__ pbn2) {
    int c = threadIdx.x & 127;
    int half = threadIdx.x >> 7;
    int r0 = blockIdx.x * 100;
    float s = 0.f;
    for (int r = r0 + half; r < r0 + 100; r += 2) s += pbn[(long)r * 128 + c];
    __shared__ float red[256];
    red[threadIdx.x] = s;
    __syncthreads();
    if (half == 0) pbn2[(long)blockIdx.x * 128 + c] = red[c] + red[128 + c];
}

// ---------------- BN finalize: 125x128 -> bnsc (scale/shift) ----------------
__global__ void bnredB_kernel(const float* __restrict__ pbn2, const float* __restrict__ gamma,
                              const float* __restrict__ beta, float* __restrict__ bnsc) {
    __shared__ float tot[128];
    int t = threadIdx.x;  // 128 threads
    float s = 0.f;
    for (int r = 0; r < BNRED_BLOCKS; ++r) s += pbn2[(long)r * 128 + t];
    tot[t] = s;
    __syncthreads();
    if (t < H) {
        float mu  = tot[t] * (1.0f / NN);
        float var = tot[H + t] * (1.0f / NN) - mu * mu;
        float sc  = rsqrtf(var + EPS) * gamma[t];
        bnsc[t]     = sc;
        bnsc[H + t] = beta[t] - mu * sc;
    }
}

// ---------------- pool stage A: 512 blocks of BN+ReLU partial sums ----------------
__global__ __launch_bounds__(256) void poolA_kernel(const float* __restrict__ conv,
                                                    const float* __restrict__ bnsc,
                                                    const int* __restrict__ gstart,
                                                    float* __restrict__ psum) {
    const int g = blockIdx.x >> 3, s = blockIdx.x & 7;
    const int n0 = gstart[g], n1 = gstart[g + 1];
    const int wave = threadIdx.x >> 6, lane = threadIdx.x & 63;
    const float sc = bnsc[lane], sh = bnsc[H + lane];
    float acc = 0.f;
    for (int n = n0 + s + 8 * wave; n < n1; n += 32)
        acc += fmaxf(fmaf(conv[(long)n * H + lane], sc, sh), 0.f);
    __shared__ float red[256];
    red[threadIdx.x] = acc;
    __syncthreads();
    if (wave == 0)
        psum[(long)blockIdx.x * H + lane] = red[lane] + red[64 + lane] + red[128 + lane] + red[192 + lane];
}

// ---------------- pool stage B + MLP readout: one wave per graph ----------------
__global__ void poolB_mlp_kernel(const float* __restrict__ psum, const int* __restrict__ gstart,
                                 const float* __restrict__ W1, const float* __restrict__ b1,
                                 const float* __restrict__ W2, const float* __restrict__ b2,
                                 const float* __restrict__ W3, const float* __restrict__ b3,
                                 float* __restrict__ out) {
    __shared__ float pl[H], y1[32], y2[16];
    const int g = blockIdx.x, t = threadIdx.x;  // 64 threads
    float s = 0.f;
#pragma unroll
    for (int k = 0; k < 8; k++) s += psum[(long)(g * 8 + k) * H + t];
    const int n0 = gstart[g], n1 = gstart[g + 1];
    pl[t] = s / fmaxf((float)(n1 - n0), 1.0f);
    __syncthreads();
    if (t < 32) {
        float v = b1[t];
        for (int k = 0; k < H; k++) v = fmaf(pl[k], W1[k * 32 + t], v);
        y1[t] = fmaxf(v, 0.f);
    }
    __syncthreads();
    if (t < 16) {
        float v = b2[t];
        for (int k = 0; k < 32; k++) v = fmaf(y1[k], W2[k * 16 + t], v);
        y2[t] = fmaxf(v, 0.f);
    }
    __syncthreads();
    if (t < NC) {
        float v = b3[t];
        for (int k = 0; k < 16; k++) v = fmaf(y2[k], W3[k * NC + t], v);
        out[(long)g * NC + t] = v;
    }
}

extern "C" void kernel_launch(void* const* d_in, const int* in_sizes, int n_in,
                              void* d_out, int out_size, void* d_ws, size_t ws_size,
                              hipStream_t stream) {
    const float* x     = (const float*)d_in[0];
    const int*   ei    = (const int*)d_in[1];
    const int*   batch = (const int*)d_in[2];
    const float* W_in  = (const float*)d_in[3];
    const float* b_in  = (const float*)d_in[4];
    const float* W_hid = (const float*)d_in[5];
    const float* b_hid = (const float*)d_in[6];
    const float* gamma = (const float*)d_in[7];
    const float* beta  = (const float*)d_in[8];
    const float* W1    = (const float*)d_in[9];
    const float* b1    = (const float*)d_in[10];
    const float* W2    = (const float*)d_in[11];
    const float* b2    = (const float*)d_in[12];
    const float* W3    = (const float*)d_in[13];
    const float* b3    = (const float*)d_in[14];
    float* out = (float*)d_out;

    const int* src = ei;
    const int* dst = ei + NE;

    // ---- workspace layout (deg|cursor adjacent -> single memset; 16B-aligned chunks) ----
    int*   deg_i  = (int*)d_ws;              // 50048
    int*   cursor = deg_i + 50048;           // 50048
    int*   ebase  = cursor + 50048;          // 50056
    int*   eidx   = ebase + 50056;           // 800000
    int*   bsum   = eidx + 800000;           // 256
    int*   gstart = bsum + 256;              // 72
    float* dis    = (float*)(gstart + 72);   // 50048
    __half* hw16  = (__half*)(dis + 50048);  // NN*H halves (dis-scaled rows, fp16)
    float* conv   = (float*)(hw16 + (long)NN * H);  // NN*H
    float* h      = conv + (long)NN * H;     // NN*H
    float* pbn    = h + (long)NN * H;        // 12500*128
    float* pbn2   = pbn + (long)GATHER_BLOCKS * 128;  // 125*128
    float* bnsc   = pbn2 + BNRED_BLOCKS * 128;        // 128
    float* psum   = bnsc + 128;              // 512*64

    const int NB_GEMM = (NN + 63) / 64;        // 782
    const int NB_E    = (NE + 255) / 256;      // 3125
    const int NB_N    = (NN + 255) / 256;      // 196

    // ---- CSR build ----
    hipMemsetAsync(deg_i, 0, 2 * 50048 * sizeof(int), stream);
    count_deg_kernel<<<NB_E, 256, 0, stream>>>(dst, deg_i);
    scan1_kernel<<<NB_SCAN, 256, 0, stream>>>(deg_i, ebase, bsum, dis);
    scan2_kernel<<<1, 256, 0, stream>>>(bsum, batch, gstart);
    scan3_kernel<<<NB_N, 256, 0, stream>>>(ebase, bsum);
    fill_kernel<<<NB_E, 256, 0, stream>>>(src, dst, ebase, cursor, eidx);

    // ---- layer 0 ----
    gemm_fin_kernel<<<NB_GEMM, 256, 0, stream>>>(x, W_in, dis, hw16);
    gather_kernel<0><<<GATHER_BLOCKS, 256, 0, stream>>>(hw16, ebase, eidx, dis, b_in, h, nullptr);

    // ---- hidden layers ----
    gemm_hid_kernel<0><<<NB_GEMM, 256, 0, stream>>>(h, W_hid, nullptr, dis, hw16);
    gather_kernel<1><<<GATHER_BLOCKS, 256, 0, stream>>>(hw16, ebase, eidx, dis, b_hid, conv, pbn);
    bnredA_kernel<<<BNRED_BLOCKS, 256, 0, stream>>>(pbn, pbn2);
    bnredB_kernel<<<1, 128, 0, stream>>>(pbn2, gamma, beta, bnsc);
    for (int l = 1; l < 3; l++) {
        gemm_hid_kernel<1><<<NB_GEMM, 256, 0, stream>>>(conv, W_hid + (long)l * H * H, bnsc, dis, hw16);
        gather_kernel<1><<<GATHER_BLOCKS, 256, 0, stream>>>(hw16, ebase, eidx, dis,
                                                            b_hid + (long)l * H, conv, pbn);
        bnredA_kernel<<<BNRED_BLOCKS, 256, 0, stream>>>(pbn, pbn2);
        bnredB_kernel<<<1, 128, 0, stream>>>(pbn2, gamma, beta, bnsc);
    }

    // ---- pool (BN+ReLU fused) + MLP ----
    poolA_kernel<<<NG * 8, 256, 0, stream>>>(conv, bnsc, gstart, psum);
    poolB_mlp_kernel<<<NG, 64, 0, stream>>>(psum, gstart, W1, b1, W2, b2, W3, b3, out);
}